// Round 6
// baseline (42709.235 us; speedup 1.0000x reference)
//
#include <hip/hip_runtime.h>
#include <hip/hip_bf16.h>

// FreqCounter: out[b,i] = lookup[item_ids[b,i]]
// item_ids: (16384,1000) int32; lookup: (120000,) f32; out f32.
// user_ids (d_in[0]) unused.
//
// R4 showed LDS-probing beats the VMEM gather wall, but the stage/probe
// phases were barrier-serialized (all pipes <40%). R5: double-buffered
// slice pipeline — table in 6 slices of 20480 floats, two 80KB LDS
// buffers (160KB total), staged by global_load_lds DMA. Counted
// s_waitcnt vmcnt(5) + RAW s_barrier (not __syncthreads, which drains
// vmcnt to 0) keeps the next slice's DMA in flight under the current
// slice's probes. Probe = sub + min-clamp + ds_read + masked select;
// miss lanes all clamp to one address (broadcast, ~free).

typedef unsigned int u32;
typedef float f32x4 __attribute__((ext_vector_type(4)));   // native vec for NT store

#define BLOCK   1024
#define QCHUNK  8              // int4 quads per thread per generation
#define NSLICES 6
#define SLICE   20480          // floats per slice (= 5 DMA rounds of 4096)
#define ROUNDS  5              // per-wave global_load_lds issues per slice
#define GRID    256

__device__ __forceinline__ void gload_lds16(const float* g, float* l) {
    __builtin_amdgcn_global_load_lds(
        (const __attribute__((address_space(1))) u32*)g,
        (__attribute__((address_space(3))) u32*)l, 16, 0, 0);
}

__global__ void __launch_bounds__(BLOCK, 4)
FreqCounter_68315749810839_kernel(
    const int* __restrict__ ids,
    const float* __restrict__ lookup,
    float* __restrict__ out,
    long n4, long qpb, int Tn)
{
    extern __shared__ float lds[];
    const int tid = threadIdx.x;
    const int wv  = tid >> 6;      // wave 0..15
    const int ln  = tid & 63;
    const int4* __restrict__ ids4 = (const int4*)ids;
    f32x4* __restrict__ out4 = (f32x4*)out;

    const long base = (long)blockIdx.x * qpb;
    long qend = base + qpb; if (qend > n4) qend = n4;
    const long GQ = (long)BLOCK * QCHUNK;
    const int gens = (int)((qpb + GQ - 1) / GQ);

    // DMA one slice into buffer bf: LDS dest is wave-uniform base + lane*16B,
    // global src is per-lane (clamped to keep 16B reads in-bounds; the
    // clamped-garbage LDS slots are never selected by the probe mask).
#define ISSUE(sl, bf)                                                        \
    {                                                                        \
        const long lo2_ = (long)(sl) * SLICE;                                \
        float* lb_ = lds + (bf) * SLICE + wv * 256;                          \
        _Pragma("unroll")                                                    \
        for (int rr = 0; rr < ROUNDS; ++rr) {                                \
            long gi = lo2_ + rr * 4096 + wv * 256 + ln * 4;                  \
            if (gi > (long)Tn - 4) gi = (long)Tn - 4;                        \
            gload_lds16(lookup + gi, lb_ + rr * 4096);                       \
        }                                                                    \
    }

#define PR1(comp)                                                            \
    {                                                                        \
        u32 d = (u32)v[q].comp - lo2;                                        \
        u32 a = d < (u32)SLICE ? d : (u32)(SLICE - 1);                       \
        float val = bptr[a];                                                 \
        if (d < (u32)SLICE) r[q].comp = val;                                 \
    }

    for (int g = 0; g < gens; ++g) {
        const long gbase = base + (long)g * GQ;

        int4 v[QCHUNK];
        f32x4 r[QCHUNK];
        bool ok[QCHUNK];
#pragma unroll
        for (int q = 0; q < QCHUNK; ++q) {
            long idx = gbase + tid + (long)q * BLOCK;
            ok[q] = idx < qend;
            v[q] = ok[q] ? ids4[idx] : make_int4(0, 0, 0, 0);
            r[q] = (f32x4)(0.f, 0.f, 0.f, 0.f);
        }

        asm volatile("" ::: "memory");
        ISSUE(0, 0);

#pragma unroll
        for (int s = 0; s < NSLICES; ++s) {
            asm volatile("" ::: "memory");
            // Safe to DMA into buf[(s+1)&1]: the trailing barrier of iter
            // s-1 guaranteed all waves finished probing that buffer.
            if (s + 1 < NSLICES) { ISSUE(s + 1, (s + 1) & 1); }
            // Wait for THIS slice's DMA (5 newest in flight are s+1's).
            if (s + 1 < NSLICES) { asm volatile("s_waitcnt vmcnt(5)" ::: "memory"); }
            else                 { asm volatile("s_waitcnt vmcnt(0)" ::: "memory"); }
            __builtin_amdgcn_s_barrier();      // everyone's slice-s DMA landed
            asm volatile("" ::: "memory");

            {
                const u32 lo2 = (u32)(s * SLICE);
                const float* bptr = lds + (s & 1) * SLICE;
#pragma unroll
                for (int q = 0; q < QCHUNK; ++q) {
                    PR1(x) PR1(y) PR1(z) PR1(w)
                }
            }

            asm volatile("" ::: "memory");
            __builtin_amdgcn_s_barrier();      // probes of s done -> buffer reusable
        }

#pragma unroll
        for (int q = 0; q < QCHUNK; ++q) {
            long idx = gbase + tid + (long)q * BLOCK;
            if (ok[q]) __builtin_nontemporal_store(r[q], &out4[idx]);
        }
    }
#undef ISSUE
#undef PR1
}

// Generic fallback (any table size / tiny n): plain VMEM gather.
__global__ void FreqCounter_fallback_kernel(
    const int* __restrict__ ids, const float* __restrict__ lookup,
    float* __restrict__ out, long n)
{
    long i = (long)blockIdx.x * blockDim.x + threadIdx.x;
    const long stride = (long)gridDim.x * blockDim.x;
    for (; i < n; i += stride) out[i] = lookup[ids[i]];
}

// Scalar tail for n % 4 != 0 (not hit for this shape).
__global__ void FreqCounter_tail_kernel(
    const int* __restrict__ ids, const float* __restrict__ lookup,
    float* __restrict__ out, long start, long n)
{
    long i = start + (long)blockIdx.x * blockDim.x + threadIdx.x;
    if (i < n) out[i] = lookup[ids[i]];
}

extern "C" void kernel_launch(void* const* d_in, const int* in_sizes, int n_in,
                              void* d_out, int out_size, void* d_ws, size_t ws_size,
                              hipStream_t stream) {
    // setup_inputs order: user_ids, item_ids, lookup
    const int*   ids    = (const int*)d_in[1];
    const float* lookup = (const float*)d_in[2];
    float*       out    = (float*)d_out;

    const long n  = (long)in_sizes[1];   // 16,384,000
    const int  Tn = in_sizes[2];         // 120,000

    if (Tn < 8 || Tn > NSLICES * SLICE || n < 4096) {
        long want = (n + 255) / 256;
        int grid = (int)(want < 2048 ? want : 2048);
        if (grid < 1) grid = 1;
        FreqCounter_fallback_kernel<<<grid, 256, 0, stream>>>(ids, lookup, out, n);
        return;
    }

    const long n4 = n / 4;
    const size_t smem = (size_t)(2 * SLICE) * sizeof(float);   // 163840 B
    (void)hipFuncSetAttribute(
        reinterpret_cast<const void*>(FreqCounter_68315749810839_kernel),
        hipFuncAttributeMaxDynamicSharedMemorySize, (int)smem);

    const long qpb = (n4 + GRID - 1) / GRID;   // 16000 quads/block
    FreqCounter_68315749810839_kernel<<<GRID, BLOCK, smem, stream>>>(
        ids, lookup, out, n4, qpb, Tn);

    const long done = n4 * 4;
    if (done < n) {
        long rem = n - done;
        int tgrid = (int)((rem + 255) / 256);
        FreqCounter_tail_kernel<<<tgrid, 256, 0, stream>>>(ids, lookup, out, done, n);
    }
}

// Round 7
// 61.752 us; speedup vs baseline: 691.6265x; 691.6265x over previous
//
#include <hip/hip_runtime.h>
#include <hip/hip_bf16.h>

// FreqCounter: out[b,i] = lookup[item_ids[b,i]]
// item_ids: (16384,1000) int32; lookup: (120000,) f32; out f32.
// user_ids (d_in[0]) unused.
//
// R4 (LDS probing, 4 slices, slice-inner) = 50.6us. R6 (inline-asm counted
// vmcnt pipeline) = codegen catastrophe (163GB scratch/write traffic).
// R7: slice-OUTER, single 160KB buffer, 3 slices of 40960 floats:
//   - probes/element: 4 (R4) -> 3; barriers: 8/gen -> 6 total per block
//   - results r[16] live in VGPRs across slices; ids re-read per slice
//     (L2/L3-resident; R4 showed the compiler remats this anyway)
//   - staging via global_load_lds DMA, linear LDS dest (wave-uniform base
//     + lane*16B), plain __syncthreads() ordering only. NO inline asm.
// Probe = sub + mask + ds_read (miss lanes broadcast lds[0], ~free).

typedef unsigned int u32;

#define BLOCK   1024
#define QTOT    16         // int4 quads per thread = 16384 quads per block
#define NSLICES 3
#define SLICE   40960      // floats per slice; LDS = 40960*4 = 163840 B (max)
#define ROUNDS  10         // SLICE / (BLOCK lanes * 4 floats)

__device__ __forceinline__ void gload_lds16(const float* g, float* l) {
    __builtin_amdgcn_global_load_lds(
        (const __attribute__((address_space(1))) u32*)g,
        (__attribute__((address_space(3))) u32*)l, 16, 0, 0);
}

__global__ void __launch_bounds__(BLOCK, 4)
FreqCounter_68315749810839_kernel(
    const int* __restrict__ ids,
    const float* __restrict__ lookup,
    float* __restrict__ out,
    long n4, int Tn)
{
    extern __shared__ float lds[];
    const int tid = threadIdx.x;
    const int wv  = tid >> 6;      // wave 0..15
    const int ln  = tid & 63;
    const int4* __restrict__ ids4 = (const int4*)ids;
    float4* __restrict__ out4 = (float4*)out;

    const long base = (long)blockIdx.x * (QTOT * BLOCK) + tid;

    float4 r[QTOT];
#pragma unroll
    for (int q = 0; q < QTOT; ++q) r[q] = make_float4(0.f, 0.f, 0.f, 0.f);

    for (int s = 0; s < NSLICES; ++s) {
        // ---- stage slice s: DMA, LDS dest = wave-uniform base + lane*16B,
        //      global src per-lane, clamped so 16B reads stay in-bounds.
        //      (Clamped-duplicate LDS slots are never selected: d >= len.)
        {
            const long lo = (long)s * SLICE;
            float* lb = lds + wv * 256;
#pragma unroll
            for (int rr = 0; rr < ROUNDS; ++rr) {
                long gi = lo + rr * 4096 + wv * 256 + ln * 4;
                if (gi > (long)Tn - 4) gi = (long)Tn - 4;
                gload_lds16(lookup + gi, lb + rr * 4096);
            }
        }
        __syncthreads();   // drains the DMA (vmcnt) + all waves arrived

        const u32 lo2 = (u32)(s * SLICE);
        const u32 rem = (u32)Tn - lo2;
        const u32 len = rem < (u32)SLICE ? rem : (u32)SLICE;

#define PR1(comp)                                                        \
        {                                                                \
            u32 d = (u32)vv.comp - lo2;                                  \
            u32 a = d < len ? d : 0u;     /* misses broadcast lds[0] */  \
            float val = lds[a];                                          \
            if (d < len) r[q].comp = val;                                \
        }
#pragma unroll
        for (int q = 0; q < QTOT; ++q) {
            long idx = base + (long)q * BLOCK;
            if (idx < n4) {
                int4 vv = ids4[idx];     // L2/L3-resident after slice 0
                PR1(x) PR1(y) PR1(z) PR1(w)
            }
        }
#undef PR1
        __syncthreads();   // all probes done before next slice overwrites
    }

#pragma unroll
    for (int q = 0; q < QTOT; ++q) {
        long idx = base + (long)q * BLOCK;
        if (idx < n4) out4[idx] = r[q];
    }
}

// Generic fallback (odd table size / tiny n): plain VMEM gather.
__global__ void FreqCounter_fallback_kernel(
    const int* __restrict__ ids, const float* __restrict__ lookup,
    float* __restrict__ out, long n)
{
    long i = (long)blockIdx.x * blockDim.x + threadIdx.x;
    const long stride = (long)gridDim.x * blockDim.x;
    for (; i < n; i += stride) out[i] = lookup[ids[i]];
}

// Scalar tail for n % 4 != 0 (not hit for this shape).
__global__ void FreqCounter_tail_kernel(
    const int* __restrict__ ids, const float* __restrict__ lookup,
    float* __restrict__ out, long start, long n)
{
    long i = start + (long)blockIdx.x * blockDim.x + threadIdx.x;
    if (i < n) out[i] = lookup[ids[i]];
}

extern "C" void kernel_launch(void* const* d_in, const int* in_sizes, int n_in,
                              void* d_out, int out_size, void* d_ws, size_t ws_size,
                              hipStream_t stream) {
    // setup_inputs order: user_ids, item_ids, lookup
    const int*   ids    = (const int*)d_in[1];
    const float* lookup = (const float*)d_in[2];
    float*       out    = (float*)d_out;

    const long n  = (long)in_sizes[1];   // 16,384,000
    const int  Tn = in_sizes[2];         // 120,000

    if (Tn < 16 || Tn > NSLICES * SLICE || n < 4096) {
        long want = (n + 255) / 256;
        int grid = (int)(want < 2048 ? want : 2048);
        if (grid < 1) grid = 1;
        FreqCounter_fallback_kernel<<<grid, 256, 0, stream>>>(ids, lookup, out, n);
        return;
    }

    const long n4 = n / 4;                                   // 4,096,000
    const long qpb = (long)QTOT * BLOCK;                     // 16,384
    const int grid = (int)((n4 + qpb - 1) / qpb);            // 250

    const size_t smem = (size_t)SLICE * sizeof(float);       // 163,840 B
    (void)hipFuncSetAttribute(
        reinterpret_cast<const void*>(FreqCounter_68315749810839_kernel),
        hipFuncAttributeMaxDynamicSharedMemorySize, (int)smem);

    FreqCounter_68315749810839_kernel<<<grid, BLOCK, smem, stream>>>(
        ids, lookup, out, n4, Tn);

    const long done = n4 * 4;
    if (done < n) {
        long rem = n - done;
        int tgrid = (int)((rem + 255) / 256);
        FreqCounter_tail_kernel<<<tgrid, 256, 0, stream>>>(ids, lookup, out, done, n);
    }
}

// Round 8
// 43.870 us; speedup vs baseline: 973.5445x; 1.4076x over previous
//
#include <hip/hip_runtime.h>
#include <hip/hip_bf16.h>

// FreqCounter: out[b,i] = lookup[item_ids[b,i]]
// item_ids: (16384,1000) int32; lookup: (120000,) f32; out f32.
// user_ids (d_in[0]) unused.
//
// Ladder: R1 VMEM gather 72us (VMEM addr-path wall) -> R4 LDS-probe 50.6us
// (barrier-serialized, all pipes <40%) -> R6 asm pipeline = codegen disaster
// -> R7 slice-outer = spills + 3x HBM ids re-read (134MB fetch).
// R8: get stage/probe overlap from TWO blocks per CU (m114: separate waves
// overlap pipes automatically) instead of intra-block pipelining:
//   - 512-thread blocks, LDS 81920 B (20480 f32) -> exactly 2 blocks/CU
//   - 6 slices of 20480 floats, slice-outer; ids held in regs (QTOT=8,
//     ~90 VGPR, no spill; ids read from HBM ONCE)
//   - DMA staging (global_load_lds, linear dest), plain __syncthreads()
//   - odd blocks walk slices in REVERSE order so co-resident blocks are
//     anti-phased: one probes (DS pipe) while the other stages (VMEM).
// Probe = sub + cmp + clamp-cndmask + ds_read + select (misses clamp to
// lds[0] = same-addr broadcast, ~free per m136).

typedef unsigned int u32;

#define BLOCK   512
#define QTOT    8          // int4 quads per thread -> 4096 quads/block
#define NSLICES 6
#define SLICE   20480      // floats per slice; LDS = 81920 B (2 blocks/CU)
#define ROUNDS  10         // SLICE / (8 waves * 64 lanes * 4 floats)

__device__ __forceinline__ void gload_lds16(const float* g, float* l) {
    __builtin_amdgcn_global_load_lds(
        (const __attribute__((address_space(1))) u32*)g,
        (__attribute__((address_space(3))) u32*)l, 16, 0, 0);
}

__global__ void __launch_bounds__(BLOCK, 4)
FreqCounter_68315749810839_kernel(
    const int* __restrict__ ids,
    const float* __restrict__ lookup,
    float* __restrict__ out,
    long n4, int Tn)
{
    extern __shared__ float lds[];
    const int tid = threadIdx.x;
    const int wv  = tid >> 6;      // wave 0..7
    const int ln  = tid & 63;
    const int4* __restrict__ ids4 = (const int4*)ids;
    float4* __restrict__ out4 = (float4*)out;

    const long base = (long)blockIdx.x * (QTOT * BLOCK) + tid;
    const bool rev = (blockIdx.x & 1);

    // Load this block's ids once into registers (overlaps first DMA).
    int4 v[QTOT];
    float4 r[QTOT];
#pragma unroll
    for (int q = 0; q < QTOT; ++q) {
        long idx = base + (long)q * BLOCK;
        v[q] = (idx < n4) ? ids4[idx] : make_int4(0, 0, 0, 0);
        r[q] = make_float4(0.f, 0.f, 0.f, 0.f);
    }

    for (int s = 0; s < NSLICES; ++s) {
        const int sl = rev ? (NSLICES - 1 - s) : s;
        const long lo = (long)sl * SLICE;

        // ---- stage slice sl: DMA, LDS dest = wave-linear (uniform base +
        //      lane*16B), global src clamped so 16B reads stay in-bounds.
        //      Clamped-duplicate slots are never selected (d >= len).
        {
            float* lb = lds + wv * 256;
#pragma unroll
            for (int rr = 0; rr < ROUNDS; ++rr) {
                long gi = lo + rr * 2048 + wv * 256 + ln * 4;
                if (gi > (long)Tn - 4) gi = (long)Tn - 4;
                gload_lds16(lookup + gi, lb + rr * 2048);
            }
        }
        __syncthreads();   // DMA drained; all waves present

        const u32 lo2 = (u32)lo;
        const u32 remn = (u32)Tn - lo2;
        const u32 len = remn < (u32)SLICE ? remn : (u32)SLICE;

#define PR1(comp)                                                        \
        {                                                                \
            u32 d = (u32)v[q].comp - lo2;                                \
            u32 a = d < len ? d : 0u;   /* misses broadcast lds[0] */    \
            float val = lds[a];                                          \
            if (d < len) r[q].comp = val;                                \
        }
#pragma unroll
        for (int q = 0; q < QTOT; ++q) {
            PR1(x) PR1(y) PR1(z) PR1(w)
        }
#undef PR1
        __syncthreads();   // probes done before next slice overwrites
    }

#pragma unroll
    for (int q = 0; q < QTOT; ++q) {
        long idx = base + (long)q * BLOCK;
        if (idx < n4) out4[idx] = r[q];
    }
}

// Generic fallback (odd table size / tiny n): plain VMEM gather.
__global__ void FreqCounter_fallback_kernel(
    const int* __restrict__ ids, const float* __restrict__ lookup,
    float* __restrict__ out, long n)
{
    long i = (long)blockIdx.x * blockDim.x + threadIdx.x;
    const long stride = (long)gridDim.x * blockDim.x;
    for (; i < n; i += stride) out[i] = lookup[ids[i]];
}

// Scalar tail for n % 4 != 0 (not hit for this shape).
__global__ void FreqCounter_tail_kernel(
    const int* __restrict__ ids, const float* __restrict__ lookup,
    float* __restrict__ out, long start, long n)
{
    long i = start + (long)blockIdx.x * blockDim.x + threadIdx.x;
    if (i < n) out[i] = lookup[ids[i]];
}

extern "C" void kernel_launch(void* const* d_in, const int* in_sizes, int n_in,
                              void* d_out, int out_size, void* d_ws, size_t ws_size,
                              hipStream_t stream) {
    // setup_inputs order: user_ids, item_ids, lookup
    const int*   ids    = (const int*)d_in[1];
    const float* lookup = (const float*)d_in[2];
    float*       out    = (float*)d_out;

    const long n  = (long)in_sizes[1];   // 16,384,000
    const int  Tn = in_sizes[2];         // 120,000

    if (Tn < 16 || Tn > NSLICES * SLICE || n < 4096) {
        long want = (n + 255) / 256;
        int grid = (int)(want < 2048 ? want : 2048);
        if (grid < 1) grid = 1;
        FreqCounter_fallback_kernel<<<grid, 256, 0, stream>>>(ids, lookup, out, n);
        return;
    }

    const long n4 = n / 4;                                   // 4,096,000
    const long qpb = (long)QTOT * BLOCK;                     // 4,096
    const int grid = (int)((n4 + qpb - 1) / qpb);            // 1000

    const size_t smem = (size_t)SLICE * sizeof(float);       // 81,920 B
    (void)hipFuncSetAttribute(
        reinterpret_cast<const void*>(FreqCounter_68315749810839_kernel),
        hipFuncAttributeMaxDynamicSharedMemorySize, (int)smem);

    FreqCounter_68315749810839_kernel<<<grid, BLOCK, smem, stream>>>(
        ids, lookup, out, n4, Tn);

    const long done = n4 * 4;
    if (done < n) {
        long rem = n - done;
        int tgrid = (int)((rem + 255) / 256);
        FreqCounter_tail_kernel<<<tgrid, 256, 0, stream>>>(ids, lookup, out, done, n);
    }
}

// Round 9
// 40.076 us; speedup vs baseline: 1065.6971x; 1.0947x over previous
//
#include <hip/hip_runtime.h>
#include <hip/hip_bf16.h>

// FreqCounter: out[b,i] = lookup[item_ids[b,i]]
// item_ids: (16384,1000) int32; lookup: (120000,) f32; out f32.
// user_ids (d_in[0]) unused.
//
// Ladder: R1 VMEM gather 72us (VMEM addr-path wall ~3cy/lane) ->
// R4 LDS-probe 4-slice 50.6us -> R8 2-blocks/CU anti-phased 6-slice 43.9us.
// R8 counters: VALUBusy 29%, 6 probes/elem -> selection work is the wall.
// R9: 3 slices of 40960 f32 = 160KB LDS, 1 block/CU, 1024 thr, QTOT=8:
//   - probes/element 6 -> 3 (halves both VALU and DS per-element cost)
//   - ids loaded ONCE into regs (R7 re-read them 3x -> 134MB HBM fetch)
//   - v[8]+r[8] = 64 VGPR, launch_bounds(1024,4) caps at 128 -> no spill
//     (R7's QTOT=16 spilled: WRITE 102MB)
//   - DMA staging (global_load_lds, linear dest), plain __syncthreads().
// Probe = sub + clamp + ds_read + select (misses broadcast lds[0], ~free).

typedef unsigned int u32;

#define BLOCK   1024
#define QTOT    8          // int4 quads per thread -> 8192 quads/block
#define NSLICES 3
#define SLICE   40960      // floats per slice; LDS = 163840 B (1 block/CU)
#define ROUNDS  10         // SLICE / (16 waves * 64 lanes * 4 floats)

__device__ __forceinline__ void gload_lds16(const float* g, float* l) {
    __builtin_amdgcn_global_load_lds(
        (const __attribute__((address_space(1))) u32*)g,
        (__attribute__((address_space(3))) u32*)l, 16, 0, 0);
}

__global__ void __launch_bounds__(BLOCK, 4)
FreqCounter_68315749810839_kernel(
    const int* __restrict__ ids,
    const float* __restrict__ lookup,
    float* __restrict__ out,
    long n4, int Tn)
{
    extern __shared__ float lds[];
    const int tid = threadIdx.x;
    const int wv  = tid >> 6;      // wave 0..15
    const int ln  = tid & 63;
    const int4* __restrict__ ids4 = (const int4*)ids;
    float4* __restrict__ out4 = (float4*)out;

    const long base = (long)blockIdx.x * (QTOT * BLOCK) + tid;

    // Load this block's ids ONCE into registers (overlaps first DMA issue).
    int4 v[QTOT];
    float4 r[QTOT];
#pragma unroll
    for (int q = 0; q < QTOT; ++q) {
        long idx = base + (long)q * BLOCK;
        v[q] = (idx < n4) ? ids4[idx] : make_int4(0, 0, 0, 0);
        r[q] = make_float4(0.f, 0.f, 0.f, 0.f);
    }

    for (int s = 0; s < NSLICES; ++s) {
        const long lo = (long)s * SLICE;

        // ---- stage slice s: DMA, LDS dest = wave-linear (uniform base +
        //      lane*16B), global src clamped so 16B reads stay in-bounds.
        //      Clamped-duplicate slots are never selected (d >= len).
        {
            float* lb = lds + wv * 256;
#pragma unroll
            for (int rr = 0; rr < ROUNDS; ++rr) {
                long gi = lo + rr * 4096 + wv * 256 + ln * 4;
                if (gi > (long)Tn - 4) gi = (long)Tn - 4;
                gload_lds16(lookup + gi, lb + rr * 4096);
            }
        }
        __syncthreads();   // DMA drained; all waves present

        const u32 lo2 = (u32)lo;
        const u32 remn = (u32)Tn - lo2;
        const u32 len = remn < (u32)SLICE ? remn : (u32)SLICE;

#define PR1(comp)                                                        \
        {                                                                \
            u32 d = (u32)v[q].comp - lo2;                                \
            u32 a = d < len ? d : 0u;   /* misses broadcast lds[0] */    \
            float val = lds[a];                                          \
            if (d < len) r[q].comp = val;                                \
        }
#pragma unroll
        for (int q = 0; q < QTOT; ++q) {
            PR1(x) PR1(y) PR1(z) PR1(w)
        }
#undef PR1
        if (s + 1 < NSLICES) __syncthreads();  // probes done before overwrite
    }

#pragma unroll
    for (int q = 0; q < QTOT; ++q) {
        long idx = base + (long)q * BLOCK;
        if (idx < n4) out4[idx] = r[q];
    }
}

// Generic fallback (odd table size / tiny n): plain VMEM gather.
__global__ void FreqCounter_fallback_kernel(
    const int* __restrict__ ids, const float* __restrict__ lookup,
    float* __restrict__ out, long n)
{
    long i = (long)blockIdx.x * blockDim.x + threadIdx.x;
    const long stride = (long)gridDim.x * blockDim.x;
    for (; i < n; i += stride) out[i] = lookup[ids[i]];
}

// Scalar tail for n % 4 != 0 (not hit for this shape).
__global__ void FreqCounter_tail_kernel(
    const int* __restrict__ ids, const float* __restrict__ lookup,
    float* __restrict__ out, long start, long n)
{
    long i = start + (long)blockIdx.x * blockDim.x + threadIdx.x;
    if (i < n) out[i] = lookup[ids[i]];
}

extern "C" void kernel_launch(void* const* d_in, const int* in_sizes, int n_in,
                              void* d_out, int out_size, void* d_ws, size_t ws_size,
                              hipStream_t stream) {
    // setup_inputs order: user_ids, item_ids, lookup
    const int*   ids    = (const int*)d_in[1];
    const float* lookup = (const float*)d_in[2];
    float*       out    = (float*)d_out;

    const long n  = (long)in_sizes[1];   // 16,384,000
    const int  Tn = in_sizes[2];         // 120,000

    if (Tn < 16 || Tn > NSLICES * SLICE || n < 4096) {
        long want = (n + 255) / 256;
        int grid = (int)(want < 2048 ? want : 2048);
        if (grid < 1) grid = 1;
        FreqCounter_fallback_kernel<<<grid, 256, 0, stream>>>(ids, lookup, out, n);
        return;
    }

    const long n4 = n / 4;                                   // 4,096,000
    const long qpb = (long)QTOT * BLOCK;                     // 8,192
    const int grid = (int)((n4 + qpb - 1) / qpb);            // 500

    const size_t smem = (size_t)SLICE * sizeof(float);       // 163,840 B
    (void)hipFuncSetAttribute(
        reinterpret_cast<const void*>(FreqCounter_68315749810839_kernel),
        hipFuncAttributeMaxDynamicSharedMemorySize, (int)smem);

    FreqCounter_68315749810839_kernel<<<grid, BLOCK, smem, stream>>>(
        ids, lookup, out, n4, Tn);

    const long done = n4 * 4;
    if (done < n) {
        long rem = n - done;
        int tgrid = (int)((rem + 255) / 256);
        FreqCounter_tail_kernel<<<tgrid, 256, 0, stream>>>(ids, lookup, out, done, n);
    }
}